// Round 14
// baseline (72.745 us; speedup 1.0000x reference)
//
#include <hip/hip_runtime.h>
#include <math.h>

// Router: B=4, S=8192, D=1024, E=64, TOP_K=2 (all fp32)
// Output layout (fp32, concatenated flat):
//   [0,       65536)   top_k_probs   [4,8192,2]
//   [65536,   131072)  selected_experts (as float) [4,8192,2]
//   [131072,  2228224) router_logits [4,8192,64]
//
// R14 = R13's 32x32x16 path (fragment maps VALIDATED by R13 pass) at
// proper occupancy. R13's regression was TLP, not the shape: grid 256 =
// 2 waves/SIMD (the same mistake as R8/R10; every 2-wave/SIMD variant
// lands 52-77us, every 4-wave/SIMD lands ~43).
//   Block = 64 tokens, 8 waves = 2 mg x 2 kh x 2 ng; wave = 32 tokens x
//   32 experts (one n-tile) x K-half. Grid 512, 2 blocks/CU, 4 waves/SIMD.
//   Per wave-step: 6 ds_read_b128 + 12 MFMA(32x32) — LDS/token HALF of
//   the 16x16 structure, MFMA ~20% cheaper per FLOP (m119).
//   Staging/seg-assignment/counted-vmcnt(4) verbatim R13 (validated).
//   Epilogue: B1 staging-quiesce -> kh-merge (area A, 17.4KB) -> B2 ->
//   ng-merge (area B at +20KB, 8.7KB) -> B3 -> final softmax/top-2.
//   All 8 waves execute B1/B2/B3. Numerics: same 6-term order, si0 then
//   si1, kh0+kh1 -> absmax class unchanged (0.015625).

typedef __attribute__((ext_vector_type(8)))  short bf16x8;
typedef __attribute__((ext_vector_type(16))) float f32x16;

static constexpr int TOKENS = 32768;
static constexpr int DDIM   = 1024;
static constexpr int NEXP   = 64;
static constexpr size_t OFF_EXP = 65536;
static constexpr size_t OFF_LOG = 131072;

// ---- W 3-level split + 32x32-B-fragment permute (validated R13) ----
// (e,k): nt=e>>5, col=e&31, kstep=k>>4, lane=col+32*((k>>3)&1), j=k&7
// dst (shorts) = ((kstep*2+nt)*64 + lane)*8 + j
__global__ void w_split3_kernel(const float* __restrict__ w,
                                short* __restrict__ w1,
                                short* __restrict__ w2,
                                short* __restrict__ w3) {
    int idx = blockIdx.x * blockDim.x + threadIdx.x;
    for (int i = idx; i < NEXP * DDIM; i += gridDim.x * blockDim.x) {
        int e = i >> 10, k = i & 1023;
        float f = w[i];
        unsigned u1 = __float_as_uint(f);
        float f1 = __uint_as_float(u1 & 0xffff0000u);
        float r1 = f - f1;
        unsigned u2 = __float_as_uint(r1);
        float f2 = __uint_as_float(u2 & 0xffff0000u);
        float r2 = r1 - f2;
        unsigned u3 = __float_as_uint(r2);
        int nt = e >> 5, col = e & 31;
        int kstep = k >> 4;
        int lane = col + 32 * ((k >> 3) & 1);
        int j = k & 7;
        size_t dst = ((size_t)(kstep * 2 + nt) * 64 + lane) * 8 + j;
        w1[dst] = (short)(u1 >> 16);
        w2[dst] = (short)(u2 >> 16);
        w3[dst] = (short)(u3 >> 16);
    }
}

__device__ inline void split8(float4 a, float4 b,
                              bf16x8& o1, bf16x8& o2, bf16x8& o3) {
    float f[8] = {a.x, a.y, a.z, a.w, b.x, b.y, b.z, b.w};
#pragma unroll
    for (int j = 0; j < 8; ++j) {
        unsigned u1 = __float_as_uint(f[j]);
        float f1 = __uint_as_float(u1 & 0xffff0000u);
        float r1 = f[j] - f1;
        unsigned u2 = __float_as_uint(r1);
        float f2 = __uint_as_float(u2 & 0xffff0000u);
        float r2 = r1 - f2;
        o1[j] = (short)(u1 >> 16);
        o2[j] = (short)(u2 >> 16);
        o3[j] = (short)(__float_as_uint(r2) >> 16);
    }
}

typedef const __attribute__((address_space(1))) unsigned int* gas1_t;
typedef __attribute__((address_space(3))) unsigned int* las3_t;
__device__ inline void stage16(const void* g, void* l) {
    __builtin_amdgcn_global_load_lds((gas1_t)(uintptr_t)g,
                                     (las3_t)(uintptr_t)l, 16, 0, 0);
}

__global__ __launch_bounds__(512, 4)
void router_mfma_kernel(const float* __restrict__ h,
                        const short* __restrict__ w1,
                        const short* __restrict__ w2,
                        const short* __restrict__ w3,
                        float* __restrict__ out) {
    // 2 staging bufs x 24 KB at smem + b*24576 ([kh][arr][q] x 1KB).
    // After B1: area A (kh-merge) at smem+0, 4 slots x 64 lanes x 17 f;
    //           area B (ng-merge) at smem+20480, 2 slots x 64 x 17 f.
    __shared__ alignas(16) char smem[49152];
    const int tid  = threadIdx.x;
    const int lane = tid & 63;
    const int wv   = tid >> 6;          // 0..7
    const int kh   = wv & 1;            // K half
    const int ng   = (wv >> 1) & 1;     // n-tile (expert half)
    const int mg   = wv >> 2;           // M group 0..1 (32 tokens)
    const int token0 = blockIdx.x * 64 + mg * 32;
    const int col  = lane & 31;         // token row (A) / expert col (B,C)
    const int hh   = lane >> 5;         // k-subgroup

    const float* ap = h + (size_t)(token0 + col) * DDIM + kh * 512 + hh * 8;

    // staging (verbatim R13): seg = wv*3+i in [0,24); kh_s=seg/12,
    // rem=seg%12, arr=rem/4, q=rem%4; src advances t*4096/step.
    const short* warr[3] = {w1, w2, w3};
    const char* gsrc[3];
    int ldso[3];
#pragma unroll
    for (int i = 0; i < 3; ++i) {
        int seg = wv * 3 + i;
        int kh_s = seg / 12;
        int rem  = seg % 12;
        int arr  = rem >> 2, q = rem & 3;
        gsrc[i] = (const char*)warr[arr] + (size_t)kh_s * 65536 + q * 1024
                + lane * 16;
        ldso[i] = kh_s * 12288 + arr * 4096 + q * 1024;
    }

#define STAGE(bb, tt)                                                      \
    {                                                                      \
        _Pragma("unroll")                                                  \
        for (int i = 0; i < 3; ++i)                                        \
            stage16(gsrc[i] + (size_t)(tt) * 4096,                         \
                    smem + (bb) * 24576 + ldso[i]);                        \
    }

    f32x16 acc;     // 32 tokens x 32 experts (this wave's n-tile)
#pragma unroll
    for (int q = 0; q < 16; ++q) acc[q] = 0.0f;

    // A ping-pong: [slot][si][lo/hi]; static indices (full unroll).
    float4 ring[2][2][2];

    // prologue: [DMA(0)x3, A(0)x4] -> retire DMA(0): vmcnt(4)
    STAGE(0, 0);
    ring[0][0][0] = *reinterpret_cast<const float4*>(ap);
    ring[0][0][1] = *reinterpret_cast<const float4*>(ap + 4);
    ring[0][1][0] = *reinterpret_cast<const float4*>(ap + 16);
    ring[0][1][1] = *reinterpret_cast<const float4*>(ap + 20);
    asm volatile("s_waitcnt vmcnt(4)" ::: "memory");
    __builtin_amdgcn_s_barrier();

#pragma unroll
    for (int t = 0; t < 16; ++t) {
        const int b = t & 1;
        if (t + 1 < 16) {
            STAGE(b ^ 1, t + 1);                    // DMA(t+1) x3
            ring[b ^ 1][0][0] =
                *reinterpret_cast<const float4*>(ap + (t + 1) * 32);
            ring[b ^ 1][0][1] =
                *reinterpret_cast<const float4*>(ap + (t + 1) * 32 + 4);
            ring[b ^ 1][1][0] =
                *reinterpret_cast<const float4*>(ap + (t + 1) * 32 + 16);
            ring[b ^ 1][1][1] =
                *reinterpret_cast<const float4*>(ap + (t + 1) * 32 + 20);
        }

        bf16x8 A1[2], A2[2], A3[2];
        split8(ring[b][0][0], ring[b][0][1], A1[0], A2[0], A3[0]);  // si=0
        split8(ring[b][1][0], ring[b][1][1], A1[1], A2[1], A3[1]);  // si=1

        const char* wb = smem + b * 24576 + kh * 12288 + lane * 16;
#pragma unroll
        for (int si = 0; si < 2; ++si) {
            const int q = si * 2 + ng;
            bf16x8 W1v = *reinterpret_cast<const bf16x8*>(wb + q * 1024);
            bf16x8 W2v = *reinterpret_cast<const bf16x8*>(wb + q * 1024 + 4096);
            bf16x8 W3v = *reinterpret_cast<const bf16x8*>(wb + q * 1024 + 8192);
            f32x16 t2 = acc;
            t2 = __builtin_amdgcn_mfma_f32_32x32x16_bf16(A3[si], W1v, t2, 0, 0, 0);
            t2 = __builtin_amdgcn_mfma_f32_32x32x16_bf16(A1[si], W3v, t2, 0, 0, 0);
            t2 = __builtin_amdgcn_mfma_f32_32x32x16_bf16(A2[si], W2v, t2, 0, 0, 0);
            t2 = __builtin_amdgcn_mfma_f32_32x32x16_bf16(A2[si], W1v, t2, 0, 0, 0);
            t2 = __builtin_amdgcn_mfma_f32_32x32x16_bf16(A1[si], W2v, t2, 0, 0, 0);
            t2 = __builtin_amdgcn_mfma_f32_32x32x16_bf16(A1[si], W1v, t2, 0, 0, 0);
            acc = t2;
        }

        if (t + 1 < 16) {
            // queue: [DMA(t+1)x3, A(t+1)x4] -> vmcnt(4) retires the DMAs
            asm volatile("s_waitcnt vmcnt(4)" ::: "memory");
            __builtin_amdgcn_s_barrier();
        }
    }

    // B1: staging region quiescent before overlays (R12's lesson).
    __syncthreads();

    // ---- merge 1: K-halves via area A (smem+0) ----
    if (kh == 1) {
        float* cA = (float*)smem + (size_t)((mg * 2 + ng) * 64 + lane) * 17;
#pragma unroll
        for (int q = 0; q < 16; ++q) cA[q] = acc[q];
    }
    __syncthreads();   // B2
    if (kh == 0) {
        const float* cA = (const float*)smem
                        + (size_t)((mg * 2 + ng) * 64 + lane) * 17;
#pragma unroll
        for (int q = 0; q < 16; ++q) acc[q] += cA[q];

        // ---- logits: each kh=0 wave writes its 32-expert half ----
#pragma unroll
        for (int q = 0; q < 16; ++q) {
            const int row = (q & 3) + 8 * (q >> 2) + 4 * hh;
            out[OFF_LOG + (size_t)(token0 + row) * NEXP + ng * 32 + col]
                = acc[q];
        }

        // ---- merge 2: ng=1 publishes via area B (smem+20480) ----
        if (ng == 1) {
            float* cB = (float*)(smem + 20480) + (size_t)(mg * 64 + lane) * 17;
#pragma unroll
            for (int q = 0; q < 16; ++q) cB[q] = acc[q];
        }
    }
    __syncthreads();   // B3
    if (kh != 0 || ng != 0) return;

    const float* cB = (const float*)(smem + 20480)
                    + (size_t)(mg * 64 + lane) * 17;

    // ---- softmax + top-2 per token (32-lane halves, xor 1..16) ----
    // expert of acc[q] = col; expert of cB[q] = 32+col;
    // token row = (q&3) + 8*(q>>2) + 4*hh.
#pragma unroll
    for (int q = 0; q < 16; ++q) {
        const int token = token0 + (q & 3) + 8 * (q >> 2) + 4 * hh;
        float p0v = acc[q], p1v = cB[q];
        float mx = fmaxf(p0v, p1v);
#pragma unroll
        for (int d = 1; d <= 16; d <<= 1) mx = fmaxf(mx, __shfl_xor(mx, d, 64));

        float e0 = expf(p0v - mx);
        float e1 = expf(p1v - mx);
        float s = e0 + e1;
#pragma unroll
        for (int d = 1; d <= 16; d <<= 1) s += __shfl_xor(s, d, 64);

        // local top-2: experts col and 32+col; lower idx wins ties
        float v1, v2; int i1, i2;
        if (e1 > e0) { v1 = e1; i1 = 32 + col; v2 = e0; i2 = col; }
        else         { v1 = e0; i1 = col;      v2 = e1; i2 = 32 + col; }

#pragma unroll
        for (int d = 1; d <= 16; d <<= 1) {
            float ov1 = __shfl_xor(v1, d, 64);
            float ov2 = __shfl_xor(v2, d, 64);
            int   oi1 = __shfl_xor(i1, d, 64);
            int   oi2 = __shfl_xor(i2, d, 64);
            bool ofirst = (ov1 > v1) || (ov1 == v1 && oi1 < i1);
            float n1, n2; int ni1, ni2;
            if (ofirst) {
                n1 = ov1; ni1 = oi1;
                bool sec = (v1 > ov2) || (v1 == ov2 && i1 < oi2);
                n2 = sec ? v1 : ov2; ni2 = sec ? i1 : oi2;
            } else {
                n1 = v1; ni1 = i1;
                bool sec = (ov1 > v2) || (ov1 == v2 && oi1 < i2);
                n2 = sec ? ov1 : v2; ni2 = sec ? oi1 : i2;
            }
            v1 = n1; i1 = ni1; v2 = n2; i2 = ni2;
        }

        if (col == 0) {
            float t1 = v1 / s;
            float t2 = v2 / s;
            float dn = t1 + t2 + 1e-8f;
            float2 pr; pr.x = t1 / dn; pr.y = t2 / dn;
            *reinterpret_cast<float2*>(out + (size_t)token * 2) = pr;
            float2 ex; ex.x = (float)i1; ex.y = (float)i2;
            *reinterpret_cast<float2*>(out + OFF_EXP + (size_t)token * 2) = ex;
        }
    }
#undef STAGE
}

extern "C" void kernel_launch(void* const* d_in, const int* in_sizes, int n_in,
                              void* d_out, int out_size, void* d_ws, size_t ws_size,
                              hipStream_t stream) {
    const float* h = (const float*)d_in[0];
    const float* w = (const float*)d_in[1];
    float* out = (float*)d_out;
    // d_ws: W1 | W2 | W3, each 65536 shorts = 384 KiB total
    short* w1 = (short*)d_ws;
    short* w2 = w1 + (size_t)NEXP * DDIM;
    short* w3 = w2 + (size_t)NEXP * DDIM;
    hipLaunchKernelGGL(w_split3_kernel, dim3(128), dim3(256), 0, stream, w, w1, w2, w3);
    hipLaunchKernelGGL(router_mfma_kernel, dim3(TOKENS / 64), dim3(512), 0, stream,
                       h, w1, w2, w3, out);
}